// Round 13
// baseline (797.875 us; speedup 1.0000x reference)
//
#include <hip/hip_runtime.h>
#include <stdint.h>

#define C_DIM 8192
#define O_DIM 8192
#define M_DIM 256
#define NG    128     // C/64 groups
#define SUPS  16      // super-iterations (8 groups each)
#define GPS   8
#define RK    32

typedef float f32x4 __attribute__((ext_vector_type(4)));
typedef int   i32x4 __attribute__((ext_vector_type(4)));
typedef unsigned int u32;

__device__ __forceinline__ void gll16(const void* g, void* l) {
  __builtin_amdgcn_global_load_lds(
      (const __attribute__((address_space(1))) void*)g,
      (__attribute__((address_space(3))) void*)l, 16, 0, 0);
}
__device__ __forceinline__ int pack4i(int a, int b, int c, int d) {
  return (a & 0xff) | ((b & 0xff) << 8) | ((c & 0xff) << 16) | (d << 24);
}
__device__ __forceinline__ int pack8(i32x4 r) {
  return (r[0] & 0xff) | ((r[1] & 0xff) << 8) | ((r[2] & 0xff) << 16) |
         (r[3] << 24);
}

// ---------------------------------------------------------------------------
// k_lora: lact[m][r] = sum_k x[m][k] * pd[k][r]   (256 x 32, f32)
// ---------------------------------------------------------------------------
__global__ __launch_bounds__(256) void k_lora(const float* __restrict__ x,
                                              const float* __restrict__ pd,
                                              float* __restrict__ lact) {
  const int t  = threadIdx.x;
  const int rq = t & 7;
  const int kc = (t >> 3) & 15;
  const int ml = t >> 7;
  const int m  = blockIdx.x * 2 + ml;
  const float* xrow = x + (size_t)m * C_DIM + kc * 512;
  const float* pdp  = pd + (size_t)(kc * 512) * RK + rq * 4;
  float a0 = 0.f, a1 = 0.f, a2 = 0.f, a3 = 0.f;
  for (int k = 0; k < 512; k += 4) {
    float4 xv = *(const float4*)(xrow + k);
    float4 p0 = *(const float4*)(pdp + (size_t)(k + 0) * RK);
    float4 p1 = *(const float4*)(pdp + (size_t)(k + 1) * RK);
    float4 p2 = *(const float4*)(pdp + (size_t)(k + 2) * RK);
    float4 p3 = *(const float4*)(pdp + (size_t)(k + 3) * RK);
    a0 += xv.x * p0.x + xv.y * p1.x + xv.z * p2.x + xv.w * p3.x;
    a1 += xv.x * p0.y + xv.y * p1.y + xv.z * p2.y + xv.w * p3.y;
    a2 += xv.x * p0.z + xv.y * p1.z + xv.z * p2.z + xv.w * p3.z;
    a3 += xv.x * p0.w + xv.y * p1.w + xv.z * p2.w + xv.w * p3.w;
  }
  __shared__ float red[2][8][16][4];
  red[ml][rq][kc][0] = a0;
  red[ml][rq][kc][1] = a1;
  red[ml][rq][kc][2] = a2;
  red[ml][rq][kc][3] = a3;
  __syncthreads();
  if (t < 64) {
    const int ml2 = t >> 5, r = t & 31, rq2 = r >> 2, j = r & 3;
    float s = 0.f;
#pragma unroll
    for (int c = 0; c < 16; ++c) s += red[ml2][rq2][c][j];
    lact[(size_t)(blockIdx.x * 2 + ml2) * RK + r] = s;
  }
}

// ---------------------------------------------------------------------------
// k_prep: smooth + per-group int4 quantize.
//   scp[g*512 + m] = ascale ; scp[g*512 + 256 + m] = 8*(sum q)*ascale
//   wsA8[(MT*NG+g)*64+l] = 16 i8: q[m=MT*16+(l&15)][k=(l>>4)*16+j]
// ---------------------------------------------------------------------------
__global__ __launch_bounds__(256) void k_prep(const float* __restrict__ x,
                                              const float* __restrict__ smooth,
                                              float* __restrict__ scp,
                                              i32x4* __restrict__ wsA8) {
  const int t    = threadIdx.x;
  const int ml   = t & 15;
  const int gl   = t >> 4;
  const int MT   = blockIdx.x >> 3;
  const int gblk = blockIdx.x & 7;
  const int m = MT * 16 + ml;
  const int g = gblk * 16 + gl;
  const float* xp = x + (size_t)m * C_DIM + g * 64;
  const float* sp = smooth + g * 64;
  float xs[64];
  float amax = 0.0f;
#pragma unroll
  for (int i = 0; i < 64; i += 4) {
    float4 xv = *(const float4*)(xp + i);
    float4 sv = *(const float4*)(sp + i);
    xs[i + 0] = xv.x / sv.x;
    xs[i + 1] = xv.y / sv.y;
    xs[i + 2] = xv.z / sv.z;
    xs[i + 3] = xv.w / sv.w;
    amax = fmaxf(amax, fabsf(xs[i + 0]));
    amax = fmaxf(amax, fabsf(xs[i + 1]));
    amax = fmaxf(amax, fabsf(xs[i + 2]));
    amax = fmaxf(amax, fabsf(xs[i + 3]));
  }
  const float ascale = fmaxf(amax / 7.0f, 1e-8f);
  int qi[64];
  int rs = 0;
#pragma unroll
  for (int i = 0; i < 64; ++i) {
    float qv = fminf(fmaxf(rintf(xs[i] / ascale), -8.0f), 7.0f);
    qi[i] = (int)qv;
    rs += qi[i];
  }
  scp[(size_t)g * 512 + m]       = ascale;
  scp[(size_t)g * 512 + 256 + m] = 8.0f * (float)rs * ascale;
  const size_t base = ((size_t)(MT * NG + g)) * 64;
#pragma unroll
  for (int lg = 0; lg < 4; ++lg) {
    const int* q = qi + lg * 16;
    i32x4 c;
#pragma unroll
    for (int dw = 0; dw < 4; ++dw)
      c[dw] = pack4i(q[dw * 4 + 0], q[dw * 4 + 1], q[dw * 4 + 2], q[dw * 4 + 3]);
    wsA8[base + lg * 16 + ml] = c;
  }
}

// ---------------------------------------------------------------------------
// k_mainT<MODE,REPS>: R8 structure, spill-free ((512,2) -> 128 VGPR).
// 512 blocks x 512 thr (8 waves). Block = 16 n x 256 m x full C.
// MODE bit0: A-stream neutered (g &= 3, 16KB hot). MODE bit1: B-stream
// neutered (sup &= 1, 64KB hot). Instruction stream/waits/barriers identical
// across modes (asm "memory" barriers block hoisting). REPS repeats the
// main loop (timing multiplier; numerics only valid for MODE=0, REPS=1).
// ---------------------------------------------------------------------------
template <int MODE, int REPS>
__global__ __launch_bounds__(512, 2) void k_mainT(
    const int* __restrict__ qw, const float* __restrict__ wsc,
    const float* __restrict__ pu, const float* __restrict__ bias,
    const float* __restrict__ scp, const i32x4* __restrict__ wsA8,
    const float* __restrict__ lact, float* __restrict__ out) {
  const int t    = threadIdx.x;
  const int n0   = blockIdx.x * 16;
  const int w    = t >> 6;
  const int l    = t & 63;
  const int lrow = l >> 4;
  const int lcol = l & 15;

  __shared__ __align__(16) char ldsB[2][16][512];   // packed-B dbuf
  __shared__ float ldsSC[2][4096];                  // 8 groups x {as,rs}
  __shared__ float ldsW[NG * 16];                   // wscale table

  for (int i = t; i < NG * 16; i += 512)
    ldsW[i] = wsc[(size_t)(i >> 4) * O_DIM + n0 + (i & 15)];

  const int sr = t >> 5, cg = t & 31;
  const int* gB = qw + (size_t)(n0 + sr) * C_DIM + cg * 16;
  const int wslot = (cg ^ (sr & 7)) * 16;
  const char* gSCb = (const char*)scp;
  const i32x4* gA0 = wsA8 + ((size_t)(w * 2 + 0) * NG) * 64 + l;
  const i32x4* gA1 = wsA8 + ((size_t)(w * 2 + 1) * NG) * 64 + l;

  __syncthreads();   // ldsW ready; clean ledger

  i32x4 br0, br1, br2, br3;
  i32x4 R0a, R0b, R1a, R1b, R2a, R2b, R3a, R3b;

#define LOADB(S)                                                               \
  br0 = __builtin_nontemporal_load((const i32x4*)(gB + (S) * 512 + 0));        \
  br1 = __builtin_nontemporal_load((const i32x4*)(gB + (S) * 512 + 4));        \
  br2 = __builtin_nontemporal_load((const i32x4*)(gB + (S) * 512 + 8));        \
  br3 = __builtin_nontemporal_load((const i32x4*)(gB + (S) * 512 + 12));
#define LOADSC(S, BUF)                                                         \
  gll16(gSCb + (size_t)(S) * 16384 + t * 16, &ldsSC[BUF][t * 4]);              \
  gll16(gSCb + (size_t)(S) * 16384 + 8192 + t * 16, &ldsSC[BUF][2048 + t * 4]);
#define PACKW(BUF)                                                             \
  {                                                                            \
    i32x4 pk = (i32x4){pack8(br0), pack8(br1), pack8(br2), pack8(br3)};        \
    *(i32x4*)&ldsB[BUF][sr][wslot] = pk;                                       \
  }

  // prologue: LOADB(0)[4] + LOADSC[2] + A g0..3 [8] = 14; vmcnt(8) keeps A
  LOADB(0)
  LOADSC(0, 0)
  R0a = gA0[0 * 64];  R0b = gA1[0 * 64];
  R1a = gA0[1 * 64];  R1b = gA1[1 * 64];
  R2a = gA0[2 * 64];  R2b = gA1[2 * 64];
  R3a = gA0[3 * 64];  R3b = gA1[3 * 64];
  asm volatile("s_waitcnt vmcnt(8)" ::: "memory");
  PACKW(0)
  asm volatile("s_waitcnt lgkmcnt(0)" ::: "memory");
  __builtin_amdgcn_s_barrier();

  f32x4 acc0 = (f32x4){0.f, 0.f, 0.f, 0.f};
  f32x4 acc1 = (f32x4){0.f, 0.f, 0.f, 0.f};
  const i32x4 z = (i32x4){0, 0, 0, 0};

#define SUBJ(J, RA, RB, VMC)                                                   \
  {                                                                            \
    asm volatile("s_waitcnt vmcnt(" #VMC ")" ::: "memory");                    \
    i32x4 bf = *(const i32x4*)&ldsB[s & 1][lcol]                               \
                   [(((J) * 4 + lrow) ^ (lcol & 7)) * 16];                     \
    const float* scb = &ldsSC[s & 1][(J) * 512];                               \
    f32x4 as0 = *(const f32x4*)(scb + (w * 2 + 0) * 16 + lrow * 4);            \
    f32x4 rs0 = *(const f32x4*)(scb + 256 + (w * 2 + 0) * 16 + lrow * 4);      \
    f32x4 as1 = *(const f32x4*)(scb + (w * 2 + 1) * 16 + lrow * 4);            \
    f32x4 rs1 = *(const f32x4*)(scb + 256 + (w * 2 + 1) * 16 + lrow * 4);      \
    const float wsv = ldsW[(s * GPS + (J)) * 16 + lcol];                       \
    i32x4 d0 = __builtin_amdgcn_mfma_i32_16x16x64_i8(RA, bf, z, 0, 0, 0);      \
    i32x4 d1 = __builtin_amdgcn_mfma_i32_16x16x64_i8(RB, bf, z, 0, 0, 0);      \
    {                                                                          \
      int gn = s * GPS + (J) + 4;                                              \
      if (gn > NG - 1) gn = NG - 1;                                            \
      if (MODE & 1) gn &= 3;                                                   \
      RA = gA0[(size_t)gn * 64];                                               \
      RB = gA1[(size_t)gn * 64];                                               \
    }                                                                          \
    f32x4 df0, df1;                                                            \
    df0[0] = (float)d0[0]; df0[1] = (float)d0[1];                              \
    df0[2] = (float)d0[2]; df0[3] = (float)d0[3];                              \
    df1[0] = (float)d1[0]; df1[1] = (float)d1[1];                              \
    df1[2] = (float)d1[2]; df1[3] = (float)d1[3];                              \
    acc0 += wsv * (as0 * df0 - rs0);                                           \
    acc1 += wsv * (as1 * df1 - rs1);                                           \
  }

  for (int rep = 0; rep < REPS; ++rep) {
    for (int s = 0; s < SUPS; ++s) {
      const int sn  = (s < SUPS - 1) ? s + 1 : SUPS - 1;
      const int snB = (MODE & 2) ? (sn & 1) : sn;
      const int nb  = (s + 1) & 1;
      LOADB(snB)
      LOADSC(sn, nb)
      SUBJ(0, R0a, R0b, 12)
      SUBJ(1, R1a, R1b, 12)
      SUBJ(2, R2a, R2b, 12)
      SUBJ(3, R3a, R3b, 12)
      SUBJ(4, R0a, R0b, 6)
      SUBJ(5, R1a, R1b, 6)
      SUBJ(6, R2a, R2b, 6)
      SUBJ(7, R3a, R3b, 6)
      asm volatile("s_waitcnt vmcnt(8)" ::: "memory");
      PACKW(nb)
      asm volatile("s_waitcnt lgkmcnt(0)" ::: "memory");
      __builtin_amdgcn_s_barrier();
    }
  }
#undef SUBJ
#undef LOADB
#undef LOADSC
#undef PACKW

  // epilogue: + bias + lora
  const int n = n0 + lcol;
  const float bv = bias[n];
  float4 puq[8];
#pragma unroll
  for (int rq = 0; rq < 8; ++rq)
    puq[rq] = *(const float4*)(pu + (size_t)n * RK + rq * 4);
#pragma unroll
  for (int mi = 0; mi < 2; ++mi) {
    const f32x4 av = (mi == 0) ? acc0 : acc1;
#pragma unroll
    for (int j = 0; j < 4; ++j) {
      const int m = (w * 2 + mi) * 16 + lrow * 4 + j;
      const float* lp = lact + (size_t)m * RK;
      float lo = 0.f;
#pragma unroll
      for (int rq = 0; rq < 8; ++rq) {
        float4 lv = *(const float4*)(lp + rq * 4);
        lo += lv.x * puq[rq].x + lv.y * puq[rq].y + lv.z * puq[rq].z +
              lv.w * puq[rq].w;
      }
      out[(size_t)m * O_DIM + n] = av[j] + bv + lo;
    }
  }
}

// ---------------------------------------------------------------------------
extern "C" void kernel_launch(void* const* d_in, const int* in_sizes, int n_in,
                              void* d_out, int out_size, void* d_ws,
                              size_t ws_size, hipStream_t stream) {
  const float* x      = (const float*)d_in[0];
  const int*   qw     = (const int*)d_in[1];
  const float* wsc    = (const float*)d_in[2];
  const float* smooth = (const float*)d_in[3];
  const float* pd     = (const float*)d_in[4];
  const float* pu     = (const float*)d_in[5];
  const float* bias   = (const float*)d_in[6];
  float* out = (float*)d_out;

  char* ws = (char*)d_ws;
  float* lact  = (float*)ws;                     // 32 KB
  float* scp   = (float*)(ws + 32 * 1024);       // 256 KB
  i32x4* wsA8  = (i32x4*)(ws + 288 * 1024);      // 2 MB
  float* dummy = (float*)(ws + 2336 * 1024);     // 8 MB ablation sink

  hipLaunchKernelGGL(k_prep, dim3(128), dim3(256), 0, stream, x, smooth, scp,
                     wsA8);
  hipLaunchKernelGGL(k_lora, dim3(128), dim3(256), 0, stream, x, pd, lact);

  // Ablations (write to dummy; numerics intentionally meaningless):
  k_mainT<1, 3><<<dim3(512), dim3(512), 0, stream>>>(qw, wsc, pu, bias, scp,
                                                     wsA8, lact, dummy);
  k_mainT<2, 2><<<dim3(512), dim3(512), 0, stream>>>(qw, wsc, pu, bias, scp,
                                                     wsA8, lact, dummy);
  k_mainT<3, 1><<<dim3(512), dim3(512), 0, stream>>>(qw, wsc, pu, bias, scp,
                                                     wsA8, lact, dummy);
  // Real kernel:
  k_mainT<0, 1><<<dim3(512), dim3(512), 0, stream>>>(qw, wsc, pu, bias, scp,
                                                     wsA8, lact, out);
}

// Round 15
// 273.583 us; speedup vs baseline: 2.9164x; 2.9164x over previous
//
#include <hip/hip_runtime.h>
#include <stdint.h>

#define C_DIM 8192
#define O_DIM 8192
#define M_DIM 256
#define NG    128     // C/64 groups
#define RK    32

typedef float f32x4 __attribute__((ext_vector_type(4)));
typedef short s16x8 __attribute__((ext_vector_type(8)));
typedef int   i32x4 __attribute__((ext_vector_type(4)));
typedef unsigned int u32;

union FragB { uint4 u; s16x8 s; };

__device__ __forceinline__ u32 f2bf(float f) {   // RTNE f32->bf16 bits
  u32 u = __float_as_uint(f);
  return (u + 0x7FFFu + ((u >> 16) & 1u)) >> 16;
}

// ---------------------------------------------------------------------------
// k_lora: lact[m][r] = sum_k x[m][k] * pd[k][r]   (256 x 32, f32)
// ---------------------------------------------------------------------------
__global__ __launch_bounds__(256) void k_lora(const float* __restrict__ x,
                                              const float* __restrict__ pd,
                                              float* __restrict__ lact) {
  const int t  = threadIdx.x;
  const int rq = t & 7;
  const int kc = (t >> 3) & 15;
  const int ml = t >> 7;
  const int m  = blockIdx.x * 2 + ml;
  const float* xrow = x + (size_t)m * C_DIM + kc * 512;
  const float* pdp  = pd + (size_t)(kc * 512) * RK + rq * 4;
  float a0 = 0.f, a1 = 0.f, a2 = 0.f, a3 = 0.f;
  for (int k = 0; k < 512; k += 4) {
    float4 xv = *(const float4*)(xrow + k);
    float4 p0 = *(const float4*)(pdp + (size_t)(k + 0) * RK);
    float4 p1 = *(const float4*)(pdp + (size_t)(k + 1) * RK);
    float4 p2 = *(const float4*)(pdp + (size_t)(k + 2) * RK);
    float4 p3 = *(const float4*)(pdp + (size_t)(k + 3) * RK);
    a0 += xv.x * p0.x + xv.y * p1.x + xv.z * p2.x + xv.w * p3.x;
    a1 += xv.x * p0.y + xv.y * p1.y + xv.z * p2.y + xv.w * p3.y;
    a2 += xv.x * p0.z + xv.y * p1.z + xv.z * p2.z + xv.w * p3.z;
    a3 += xv.x * p0.w + xv.y * p1.w + xv.z * p2.w + xv.w * p3.w;
  }
  __shared__ float red[2][8][16][4];
  red[ml][rq][kc][0] = a0;
  red[ml][rq][kc][1] = a1;
  red[ml][rq][kc][2] = a2;
  red[ml][rq][kc][3] = a3;
  __syncthreads();
  if (t < 64) {
    const int ml2 = t >> 5, r = t & 31, rq2 = r >> 2, j = r & 3;
    float s = 0.f;
#pragma unroll
    for (int c = 0; c < 16; ++c) s += red[ml2][rq2][c][j];
    lact[(size_t)(blockIdx.x * 2 + ml2) * RK + r] = s;
  }
}

// ---------------------------------------------------------------------------
// k_prep: smooth + per-group int4 quantize + dequant to bf16 MFMA A-frags.
// xq[(MT*NG+g)*128 + kh*64 + lr*16 + ml] = uint4 of 8 bf16:
//   x_deq[m=MT*16+ml][k=g*64+kh*32+lr*8+j],  x_deq = clip(round(xs/as))*as
// ---------------------------------------------------------------------------
__global__ __launch_bounds__(256) void k_prep(const float* __restrict__ x,
                                              const float* __restrict__ smooth,
                                              uint4* __restrict__ xq) {
  const int t    = threadIdx.x;
  const int ml   = t & 15;
  const int gl   = t >> 4;
  const int MT   = blockIdx.x >> 3;
  const int gblk = blockIdx.x & 7;
  const int m = MT * 16 + ml;
  const int g = gblk * 16 + gl;
  const float* xp = x + (size_t)m * C_DIM + g * 64;
  const float* sp = smooth + g * 64;
  float xs[64];
  float amax = 0.0f;
#pragma unroll
  for (int i = 0; i < 64; i += 4) {
    float4 xv = *(const float4*)(xp + i);
    float4 sv = *(const float4*)(sp + i);
    xs[i + 0] = xv.x / sv.x;
    xs[i + 1] = xv.y / sv.y;
    xs[i + 2] = xv.z / sv.z;
    xs[i + 3] = xv.w / sv.w;
    amax = fmaxf(amax, fabsf(xs[i + 0]));
    amax = fmaxf(amax, fabsf(xs[i + 1]));
    amax = fmaxf(amax, fabsf(xs[i + 2]));
    amax = fmaxf(amax, fabsf(xs[i + 3]));
  }
  const float ascale = fmaxf(amax / 7.0f, 1e-8f);
  u32 b[64];
#pragma unroll
  for (int i = 0; i < 64; ++i) {
    float qv = fminf(fmaxf(rintf(xs[i] / ascale), -8.0f), 7.0f);
    b[i] = f2bf(qv * ascale);   // reference: q_act * ascales (f32), then bf16
  }
  const size_t base = (size_t)(MT * NG + g) * 128;
#pragma unroll
  for (int kh = 0; kh < 2; ++kh) {
#pragma unroll
    for (int lr = 0; lr < 4; ++lr) {
      const int i0 = kh * 32 + lr * 8;
      uint4 c;
      c.x = b[i0 + 0] | (b[i0 + 1] << 16);
      c.y = b[i0 + 2] | (b[i0 + 3] << 16);
      c.z = b[i0 + 4] | (b[i0 + 5] << 16);
      c.w = b[i0 + 6] | (b[i0 + 7] << 16);
      xq[base + kh * 64 + lr * 16 + ml] = c;
    }
  }
}

// ---------------------------------------------------------------------------
// k_main: pure bf16 GEMM, scales folded at staging. 256 blocks x 512 thr
// (8 waves, 1 block/CU). Block = 32 n x 256 m x full C; wave = 2mt x 2nt.
// Per sup (8 groups = 512 k): stage raw qweight (reg, nontemporal, 2KB/row)
// -> dequant bf16 (fma(c, ws, -8ws)) -> frag-order LDS (reads contiguous,
// conflict-free). Inner loop per group/wave: 4 ds_read_b128 + 4 A-loads
// (L2-hot xq) + 8 MFMA. No scales, no cvt, no manual vmcnt.
// ---------------------------------------------------------------------------
__global__ __launch_bounds__(512, 2) void k_main(
    const int* __restrict__ qw, const float* __restrict__ wsc,
    const float* __restrict__ pu, const float* __restrict__ bias,
    const uint4* __restrict__ xq, const float* __restrict__ lact,
    float* __restrict__ out) {
  const int t    = threadIdx.x;
  const int n0   = blockIdx.x * 32;
  const int w    = t >> 6;
  const int l    = t & 63;
  const int lrow = l >> 4;
  const int lcol = l & 15;

  __shared__ uint4 ldsB[2][2048];   // 2 x 32KB bf16 W frags (frag-order)
  __shared__ float ldsWS[NG * 32];  // 16KB wscale column table

  for (int i = t; i < NG * 32; i += 512)
    ldsWS[i] = wsc[(size_t)(i >> 5) * O_DIM + n0 + (i & 31)];

  // staging ids: thread -> n-row sr (32), k-chunk sc (16 x 32k)
  const int sr = t >> 4, sc = t & 15;
  const int g8s = sc >> 1, khs = sc & 1;
  const int ntw = sr >> 4, lcw = sr & 15;
  const int* gB = qw + (size_t)(n0 + sr) * C_DIM + sc * 32;
  const int fIdx = (g8s * 4 + ntw * 2 + khs) * 64;
  const int wsl0 = (0 * 16 + lcw) ^ g8s;
  const int wsl1 = (1 * 16 + lcw) ^ g8s;
  const int wsl2 = (2 * 16 + lcw) ^ g8s;
  const int wsl3 = (3 * 16 + lcw) ^ g8s;
  const size_t aBase0 = (size_t)(w * 2 + 0) * NG * 128 + l;
  const size_t aBase1 = (size_t)(w * 2 + 1) * NG * 128 + l;

  __syncthreads();

  i32x4 r0, r1, r2, r3, r4, r5, r6, r7;
  FragB AE0, AE1, AE2, AE3, AO0, AO1, AO2, AO3;

#define NTL(p) __builtin_nontemporal_load((const i32x4*)(p))
#define RAWLOAD(S)                                                             \
  r0 = NTL(gB + (S) * 512 + 0);  r1 = NTL(gB + (S) * 512 + 4);                 \
  r2 = NTL(gB + (S) * 512 + 8);  r3 = NTL(gB + (S) * 512 + 12);                \
  r4 = NTL(gB + (S) * 512 + 16); r5 = NTL(gB + (S) * 512 + 20);                \
  r6 = NTL(gB + (S) * 512 + 24); r7 = NTL(gB + (S) * 512 + 28);
#define DQ2(v0, v1) (f2bf(fmaf((float)(v0), wsv, mw8)) |                       \
                     (f2bf(fmaf((float)(v1), wsv, mw8)) << 16))
#define DEQW(BUF, S)                                                           \
  {                                                                            \
    const float wsv = ldsWS[((S) * 8 + g8s) * 32 + sr];                        \
    const float mw8 = -8.0f * wsv;                                             \
    uint4 c0, c1, c2, c3;                                                      \
    c0.x = DQ2(r0[0], r0[1]); c0.y = DQ2(r0[2], r0[3]);                        \
    c0.z = DQ2(r1[0], r1[1]); c0.w = DQ2(r1[2], r1[3]);                        \
    c1.x = DQ2(r2[0], r2[1]); c1.y = DQ2(r2[2], r2[3]);                        \
    c1.z = DQ2(r3[0], r3[1]); c1.w = DQ2(r3[2], r3[3]);                        \
    c2.x = DQ2(r4[0], r4[1]); c2.y = DQ2(r4[2], r4[3]);                        \
    c2.z = DQ2(r5[0], r5[1]); c2.w = DQ2(r5[2], r5[3]);                        \
    c3.x = DQ2(r6[0], r6[1]); c3.y = DQ2(r6[2], r6[3]);                        \
    c3.z = DQ2(r7[0], r7[1]); c3.w = DQ2(r7[2], r7[3]);                        \
    ldsB[BUF][fIdx + wsl0] = c0;                                               \
    ldsB[BUF][fIdx + wsl1] = c1;                                               \
    ldsB[BUF][fIdx + wsl2] = c2;                                               \
    ldsB[BUF][fIdx + wsl3] = c3;                                               \
  }
#define LOADA(Pa, Pb, Pc, Pd, G)                                               \
  {                                                                            \
    const size_t o = (size_t)(G) * 128;                                        \
    Pa.u = xq[aBase0 + o];      Pb.u = xq[aBase0 + o + 64];                    \
    Pc.u = xq[aBase1 + o];      Pd.u = xq[aBase1 + o + 64];                    \
  }
#define MFMA(a, b, c) __builtin_amdgcn_mfma_f32_16x16x32_bf16(a, b, c, 0, 0, 0)
#define GROUP(G8, Pa, Pb, Pc, Pd)                                              \
  {                                                                            \
    const int fb = (G8) * 256, ls = l ^ (G8);                                  \
    FragB w00, w01, w10, w11;                                                  \
    w00.u = ldsB[buf][fb + 0 + ls];                                            \
    w01.u = ldsB[buf][fb + 64 + ls];                                           \
    w10.u = ldsB[buf][fb + 128 + ls];                                          \
    w11.u = ldsB[buf][fb + 192 + ls];                                          \
    acc00 = MFMA(Pa.s, w00.s, acc00); acc00 = MFMA(Pb.s, w01.s, acc00);        \
    acc01 = MFMA(Pa.s, w10.s, acc01); acc01 = MFMA(Pb.s, w11.s, acc01);        \
    acc10 = MFMA(Pc.s, w00.s, acc10); acc10 = MFMA(Pd.s, w01.s, acc10);       \
    acc11 = MFMA(Pc.s, w10.s, acc11); acc11 = MFMA(Pd.s, w11.s, acc11);        \
  }

  // prologue: stage sup0 into buf0; A for groups 0,1
  RAWLOAD(0)
  DEQW(0, 0)
  asm volatile("s_waitcnt lgkmcnt(0)" ::: "memory");
  __builtin_amdgcn_s_barrier();
  LOADA(AE0, AE1, AE2, AE3, 0)
  LOADA(AO0, AO1, AO2, AO3, 1)

  f32x4 acc00 = (f32x4){0.f, 0.f, 0.f, 0.f};
  f32x4 acc01 = (f32x4){0.f, 0.f, 0.f, 0.f};
  f32x4 acc10 = (f32x4){0.f, 0.f, 0.f, 0.f};
  f32x4 acc11 = (f32x4){0.f, 0.f, 0.f, 0.f};

#define CLMP(G) (((G) < NG) ? (G) : (NG - 1))
  for (int s = 0; s < 16; ++s) {
    const int buf = s & 1;
    const int sn = (s < 15) ? s + 1 : 15;
    RAWLOAD(sn)
    const int gb = s * 8;
    GROUP(0, AE0, AE1, AE2, AE3) LOADA(AE0, AE1, AE2, AE3, CLMP(gb + 2))
    GROUP(1, AO0, AO1, AO2, AO3) LOADA(AO0, AO1, AO2, AO3, CLMP(gb + 3))
    GROUP(2, AE0, AE1, AE2, AE3) LOADA(AE0, AE1, AE2, AE3, CLMP(gb + 4))
    GROUP(3, AO0, AO1, AO2, AO3) LOADA(AO0, AO1, AO2, AO3, CLMP(gb + 5))
    GROUP(4, AE0, AE1, AE2, AE3) LOADA(AE0, AE1, AE2, AE3, CLMP(gb + 6))
    GROUP(5, AO0, AO1, AO2, AO3) LOADA(AO0, AO1, AO2, AO3, CLMP(gb + 7))
    GROUP(6, AE0, AE1, AE2, AE3) LOADA(AE0, AE1, AE2, AE3, CLMP(gb + 8))
    GROUP(7, AO0, AO1, AO2, AO3) LOADA(AO0, AO1, AO2, AO3, CLMP(gb + 9))
    DEQW(buf ^ 1, sn)
    asm volatile("s_waitcnt lgkmcnt(0)" ::: "memory");
    __builtin_amdgcn_s_barrier();
  }
#undef GROUP
#undef LOADA
#undef DEQW
#undef RAWLOAD

  // epilogue: + bias + lora
#pragma unroll
  for (int ni = 0; ni < 2; ++ni) {
    const int n = n0 + ni * 16 + lcol;
    const float bv = bias[n];
    float4 puq[8];
#pragma unroll
    for (int rq = 0; rq < 8; ++rq)
      puq[rq] = *(const float4*)(pu + (size_t)n * RK + rq * 4);
#pragma unroll
    for (int mi = 0; mi < 2; ++mi) {
      const f32x4 av = (mi == 0) ? (ni == 0 ? acc00 : acc01)
                                 : (ni == 0 ? acc10 : acc11);
#pragma unroll
      for (int j = 0; j < 4; ++j) {
        const int m = (w * 2 + mi) * 16 + lrow * 4 + j;
        const float* lp = lact + (size_t)m * RK;
        float lo = 0.f;
#pragma unroll
        for (int rq = 0; rq < 8; ++rq) {
          float4 lv = *(const float4*)(lp + rq * 4);
          lo += lv.x * puq[rq].x + lv.y * puq[rq].y + lv.z * puq[rq].z +
                lv.w * puq[rq].w;
        }
        out[(size_t)m * O_DIM + n] = av[j] + bv + lo;
      }
    }
  }
}

// ---------------------------------------------------------------------------
extern "C" void kernel_launch(void* const* d_in, const int* in_sizes, int n_in,
                              void* d_out, int out_size, void* d_ws,
                              size_t ws_size, hipStream_t stream) {
  const float* x      = (const float*)d_in[0];
  const int*   qw     = (const int*)d_in[1];
  const float* wsc    = (const float*)d_in[2];
  const float* smooth = (const float*)d_in[3];
  const float* pd     = (const float*)d_in[4];
  const float* pu     = (const float*)d_in[5];
  const float* bias   = (const float*)d_in[6];
  float* out = (float*)d_out;

  char* ws = (char*)d_ws;
  float* lact = (float*)ws;                 // 32 KB
  uint4* xq   = (uint4*)(ws + 32 * 1024);   // 4 MB bf16 x_deq fragments

  hipLaunchKernelGGL(k_prep, dim3(128), dim3(256), 0, stream, x, smooth, xq);
  hipLaunchKernelGGL(k_lora, dim3(128), dim3(256), 0, stream, x, pd, lact);
  hipLaunchKernelGGL(k_main, dim3(256), dim3(512), 0, stream, qw, wsc, pu,
                     bias, xq, lact, out);
}

// Round 16
// 212.118 us; speedup vs baseline: 3.7615x; 1.2898x over previous
//
#include <hip/hip_runtime.h>
#include <stdint.h>

#define C_DIM 8192
#define O_DIM 8192
#define M_DIM 256
#define NG    128     // C/64 groups
#define RK    32

typedef float f32x4 __attribute__((ext_vector_type(4)));
typedef short s16x8 __attribute__((ext_vector_type(8)));
typedef int   i32x4 __attribute__((ext_vector_type(4)));
typedef unsigned int u32;

union FragB { uint4 u; s16x8 s; };

__device__ __forceinline__ u32 f2bf(float f) {   // RTNE f32->bf16 bits
  u32 u = __float_as_uint(f);
  return (u + 0x7FFFu + ((u >> 16) & 1u)) >> 16;
}

// ---------------------------------------------------------------------------
// k_lora: lact[m][r] = sum_k x[m][k] * pd[k][r]   (256 x 32, f32)
// ---------------------------------------------------------------------------
__global__ __launch_bounds__(256) void k_lora(const float* __restrict__ x,
                                              const float* __restrict__ pd,
                                              float* __restrict__ lact) {
  const int t  = threadIdx.x;
  const int rq = t & 7;
  const int kc = (t >> 3) & 15;
  const int ml = t >> 7;
  const int m  = blockIdx.x * 2 + ml;
  const float* xrow = x + (size_t)m * C_DIM + kc * 512;
  const float* pdp  = pd + (size_t)(kc * 512) * RK + rq * 4;
  float a0 = 0.f, a1 = 0.f, a2 = 0.f, a3 = 0.f;
  for (int k = 0; k < 512; k += 4) {
    float4 xv = *(const float4*)(xrow + k);
    float4 p0 = *(const float4*)(pdp + (size_t)(k + 0) * RK);
    float4 p1 = *(const float4*)(pdp + (size_t)(k + 1) * RK);
    float4 p2 = *(const float4*)(pdp + (size_t)(k + 2) * RK);
    float4 p3 = *(const float4*)(pdp + (size_t)(k + 3) * RK);
    a0 += xv.x * p0.x + xv.y * p1.x + xv.z * p2.x + xv.w * p3.x;
    a1 += xv.x * p0.y + xv.y * p1.y + xv.z * p2.y + xv.w * p3.y;
    a2 += xv.x * p0.z + xv.y * p1.z + xv.z * p2.z + xv.w * p3.z;
    a3 += xv.x * p0.w + xv.y * p1.w + xv.z * p2.w + xv.w * p3.w;
  }
  __shared__ float red[2][8][16][4];
  red[ml][rq][kc][0] = a0;
  red[ml][rq][kc][1] = a1;
  red[ml][rq][kc][2] = a2;
  red[ml][rq][kc][3] = a3;
  __syncthreads();
  if (t < 64) {
    const int ml2 = t >> 5, r = t & 31, rq2 = r >> 2, j = r & 3;
    float s = 0.f;
#pragma unroll
    for (int c = 0; c < 16; ++c) s += red[ml2][rq2][c][j];
    lact[(size_t)(blockIdx.x * 2 + ml2) * RK + r] = s;
  }
}

// ---------------------------------------------------------------------------
// k_prep: smooth + per-group int4 quantize + dequant to bf16 MFMA A-frags.
// xq[(MT*NG+g)*128 + kh*64 + lr*16 + ml] = uint4 of 8 bf16:
//   x_deq[m=MT*16+ml][k=g*64+kh*32+lr*8+j]
// ---------------------------------------------------------------------------
__global__ __launch_bounds__(256) void k_prep(const float* __restrict__ x,
                                              const float* __restrict__ smooth,
                                              uint4* __restrict__ xq) {
  const int t    = threadIdx.x;
  const int ml   = t & 15;
  const int gl   = t >> 4;
  const int MT   = blockIdx.x >> 3;
  const int gblk = blockIdx.x & 7;
  const int m = MT * 16 + ml;
  const int g = gblk * 16 + gl;
  const float* xp = x + (size_t)m * C_DIM + g * 64;
  const float* sp = smooth + g * 64;
  float xs[64];
  float amax = 0.0f;
#pragma unroll
  for (int i = 0; i < 64; i += 4) {
    float4 xv = *(const float4*)(xp + i);
    float4 sv = *(const float4*)(sp + i);
    xs[i + 0] = xv.x / sv.x;
    xs[i + 1] = xv.y / sv.y;
    xs[i + 2] = xv.z / sv.z;
    xs[i + 3] = xv.w / sv.w;
    amax = fmaxf(amax, fabsf(xs[i + 0]));
    amax = fmaxf(amax, fabsf(xs[i + 1]));
    amax = fmaxf(amax, fabsf(xs[i + 2]));
    amax = fmaxf(amax, fabsf(xs[i + 3]));
  }
  const float ascale = fmaxf(amax / 7.0f, 1e-8f);
  u32 b[64];
#pragma unroll
  for (int i = 0; i < 64; ++i) {
    float qv = fminf(fmaxf(rintf(xs[i] / ascale), -8.0f), 7.0f);
    b[i] = f2bf(qv * ascale);
  }
  const size_t base = (size_t)(MT * NG + g) * 128;
#pragma unroll
  for (int kh = 0; kh < 2; ++kh) {
#pragma unroll
    for (int lr = 0; lr < 4; ++lr) {
      const int i0 = kh * 32 + lr * 8;
      uint4 c;
      c.x = b[i0 + 0] | (b[i0 + 1] << 16);
      c.y = b[i0 + 2] | (b[i0 + 3] << 16);
      c.z = b[i0 + 4] | (b[i0 + 5] << 16);
      c.w = b[i0 + 6] | (b[i0 + 7] << 16);
      xq[base + kh * 64 + lr * 16 + ml] = c;
    }
  }
}

// ---------------------------------------------------------------------------
// k_main: pure bf16 GEMM. 256 blocks x 512 thr (8 waves), 2 blocks/CU
// (48KB LDS, ~90 VGPR -> no spills). Block = 32 n x 256 m x full C.
// Sup = 4 groups (256 k). Per thread per sup: 4x dwordx4 raw (16 k of ONE
// group) -> dequant fma(c,ws,-8ws) -> 2x b128 frag-order LDS writes.
// Inner loop per group/wave: 4 conflict-free b128 reads + 4 A-loads (L2-hot
// xq) + 8 MFMA. No scales/cvt in loop, compiler-tracked waits only.
// ---------------------------------------------------------------------------
__global__ __launch_bounds__(512, 2) void k_main(
    const int* __restrict__ qw, const float* __restrict__ wsc,
    const float* __restrict__ pu, const float* __restrict__ bias,
    const uint4* __restrict__ xq, const float* __restrict__ lact,
    float* __restrict__ out) {
  const int t    = threadIdx.x;
  const int n0   = blockIdx.x * 32;
  const int w    = t >> 6;
  const int l    = t & 63;
  const int lrow = l >> 4;
  const int lcol = l & 15;

  __shared__ uint4 ldsB[2][1024];   // 2 x 16KB bf16 W frags (4 groups each)
  __shared__ float ldsWS[NG * 32];  // 16KB wscale column table

  for (int i = t; i < NG * 32; i += 512)
    ldsWS[i] = wsc[(size_t)(i >> 5) * O_DIM + n0 + (i & 31)];

  // staging: thread -> n-row sr (32), 16 contiguous k at sc*16 (one group)
  const int sr = t >> 4, sc = t & 15;
  const int g4s = sc >> 2;            // group within sup
  const int khs = (sc >> 1) & 1;      // 32-k half
  const int sl0 = (sc & 1) * 2;       // first 8-k slice in half
  const int ntw = sr >> 4, lcw = sr & 15;
  const int* gB = qw + (size_t)(n0 + sr) * C_DIM + sc * 16;
  const int F = g4s * 4 + ntw * 2 + khs;
  const int wA = F * 64 + ((sl0 * 16 + lcw) ^ g4s);
  const int wB = F * 64 + (((sl0 + 1) * 16 + lcw) ^ g4s);
  const size_t aBase0 = (size_t)(w * 2 + 0) * NG * 128 + l;
  const size_t aBase1 = (size_t)(w * 2 + 1) * NG * 128 + l;

  __syncthreads();

  i32x4 r0, r1, r2, r3;
  FragB AE0, AE1, AE2, AE3, AO0, AO1, AO2, AO3;

#define NTL(p) __builtin_nontemporal_load((const i32x4*)(p))
#define RAWLOAD(S)                                                             \
  r0 = NTL(gB + (S) * 256 + 0); r1 = NTL(gB + (S) * 256 + 4);                  \
  r2 = NTL(gB + (S) * 256 + 8); r3 = NTL(gB + (S) * 256 + 12);
#define DQ2(v0, v1) (f2bf(fmaf((float)(v0), wsv, mw8)) |                       \
                     (f2bf(fmaf((float)(v1), wsv, mw8)) << 16))
#define DEQW(BUF, S)                                                           \
  {                                                                            \
    const float wsv = ldsWS[((S) * 4 + g4s) * 32 + sr];                        \
    const float mw8 = -8.0f * wsv;                                             \
    uint4 c0, c1;                                                              \
    c0.x = DQ2(r0[0], r0[1]); c0.y = DQ2(r0[2], r0[3]);                        \
    c0.z = DQ2(r1[0], r1[1]); c0.w = DQ2(r1[2], r1[3]);                        \
    c1.x = DQ2(r2[0], r2[1]); c1.y = DQ2(r2[2], r2[3]);                        \
    c1.z = DQ2(r3[0], r3[1]); c1.w = DQ2(r3[2], r3[3]);                        \
    ldsB[BUF][wA] = c0;                                                        \
    ldsB[BUF][wB] = c1;                                                        \
  }
#define LOADA(Pa, Pb, Pc, Pd, G)                                               \
  {                                                                            \
    const size_t o = (size_t)(G) * 128;                                        \
    Pa.u = xq[aBase0 + o];      Pb.u = xq[aBase0 + o + 64];                    \
    Pc.u = xq[aBase1 + o];      Pd.u = xq[aBase1 + o + 64];                    \
  }
#define MFMA(a, b, c) __builtin_amdgcn_mfma_f32_16x16x32_bf16(a, b, c, 0, 0, 0)
#define GROUP(G, Pa, Pb, Pc, Pd)                                               \
  {                                                                            \
    const int fb = (G) * 256, ls = l ^ (G);                                    \
    FragB w00, w01, w10, w11;                                                  \
    w00.u = ldsB[buf][fb + 0 + ls];                                            \
    w01.u = ldsB[buf][fb + 64 + ls];                                           \
    w10.u = ldsB[buf][fb + 128 + ls];                                          \
    w11.u = ldsB[buf][fb + 192 + ls];                                          \
    acc00 = MFMA(Pa.s, w00.s, acc00); acc00 = MFMA(Pb.s, w01.s, acc00);        \
    acc01 = MFMA(Pa.s, w10.s, acc01); acc01 = MFMA(Pb.s, w11.s, acc01);        \
    acc10 = MFMA(Pc.s, w00.s, acc10); acc10 = MFMA(Pd.s, w01.s, acc10);        \
    acc11 = MFMA(Pc.s, w10.s, acc11); acc11 = MFMA(Pd.s, w11.s, acc11);        \
  }

  // prologue: stage sup0 into buf0; A for groups 0,1
  RAWLOAD(0)
  DEQW(0, 0)
  asm volatile("s_waitcnt lgkmcnt(0)" ::: "memory");
  __builtin_amdgcn_s_barrier();
  LOADA(AE0, AE1, AE2, AE3, 0)
  LOADA(AO0, AO1, AO2, AO3, 1)

  f32x4 acc00 = (f32x4){0.f, 0.f, 0.f, 0.f};
  f32x4 acc01 = (f32x4){0.f, 0.f, 0.f, 0.f};
  f32x4 acc10 = (f32x4){0.f, 0.f, 0.f, 0.f};
  f32x4 acc11 = (f32x4){0.f, 0.f, 0.f, 0.f};

#define CLMP(G) (((G) < NG) ? (G) : (NG - 1))
  for (int s = 0; s < 32; ++s) {
    const int buf = s & 1;
    const int sn = (s < 31) ? s + 1 : 31;
    RAWLOAD(sn)
    const int gb = s * 4;
    GROUP(0, AE0, AE1, AE2, AE3) LOADA(AE0, AE1, AE2, AE3, CLMP(gb + 2))
    GROUP(1, AO0, AO1, AO2, AO3) LOADA(AO0, AO1, AO2, AO3, CLMP(gb + 3))
    GROUP(2, AE0, AE1, AE2, AE3) LOADA(AE0, AE1, AE2, AE3, CLMP(gb + 4))
    GROUP(3, AO0, AO1, AO2, AO3) LOADA(AO0, AO1, AO2, AO3, CLMP(gb + 5))
    DEQW(buf ^ 1, sn)
    asm volatile("s_waitcnt lgkmcnt(0)" ::: "memory");
    __builtin_amdgcn_s_barrier();
  }
#undef GROUP
#undef LOADA
#undef DEQW
#undef RAWLOAD

  // epilogue: + bias + lora
#pragma unroll
  for (int ni = 0; ni < 2; ++ni) {
    const int n = n0 + ni * 16 + lcol;
    const float bv = bias[n];
    float4 puq[8];
#pragma unroll
    for (int rq = 0; rq < 8; ++rq)
      puq[rq] = *(const float4*)(pu + (size_t)n * RK + rq * 4);
#pragma unroll
    for (int mi = 0; mi < 2; ++mi) {
      const f32x4 av = (mi == 0) ? (ni == 0 ? acc00 : acc01)
                                 : (ni == 0 ? acc10 : acc11);
#pragma unroll
      for (int j = 0; j < 4; ++j) {
        const int m = (w * 2 + mi) * 16 + lrow * 4 + j;
        const float* lp = lact + (size_t)m * RK;
        float lo = 0.f;
#pragma unroll
        for (int rq = 0; rq < 8; ++rq) {
          float4 lv = *(const float4*)(lp + rq * 4);
          lo += lv.x * puq[rq].x + lv.y * puq[rq].y + lv.z * puq[rq].z +
                lv.w * puq[rq].w;
        }
        out[(size_t)m * O_DIM + n] = av[j] + bv + lo;
      }
    }
  }
}

// ---------------------------------------------------------------------------
extern "C" void kernel_launch(void* const* d_in, const int* in_sizes, int n_in,
                              void* d_out, int out_size, void* d_ws,
                              size_t ws_size, hipStream_t stream) {
  const float* x      = (const float*)d_in[0];
  const int*   qw     = (const int*)d_in[1];
  const float* wsc    = (const float*)d_in[2];
  const float* smooth = (const float*)d_in[3];
  const float* pd     = (const float*)d_in[4];
  const float* pu     = (const float*)d_in[5];
  const float* bias   = (const float*)d_in[6];
  float* out = (float*)d_out;

  char* ws = (char*)d_ws;
  float* lact = (float*)ws;                 // 32 KB
  uint4* xq   = (uint4*)(ws + 32 * 1024);   // 4 MB bf16 x_deq fragments

  hipLaunchKernelGGL(k_prep, dim3(128), dim3(256), 0, stream, x, smooth, xq);
  hipLaunchKernelGGL(k_lora, dim3(128), dim3(256), 0, stream, x, pd, lact);
  hipLaunchKernelGGL(k_main, dim3(256), dim3(512), 0, stream, qw, wsc, pu,
                     bias, xq, lact, out);
}